// Round 1
// baseline (1586.177 us; speedup 1.0000x reference)
//
#include <hip/hip_runtime.h>

#define DEVI __device__ __forceinline__

typedef __attribute__((ext_vector_type(8))) short s16x8;
typedef __attribute__((ext_vector_type(4))) float f32x4;
typedef unsigned short u16;

// ---------- helpers ----------
DEVI u16 f2bf(float f){
  unsigned u = __float_as_uint(f);
  u += 0x7FFFu + ((u >> 16) & 1u);     // round-to-nearest-even
  return (u16)(u >> 16);
}
DEVI float bf2f(u16 s){ return __uint_as_float(((unsigned)s) << 16); }

DEVI void gload16(const void* g, void* l){
  __builtin_amdgcn_global_load_lds((const __attribute__((address_space(1))) void*)g,
                                   (__attribute__((address_space(3))) void*)l, 16, 0, 0);
}

// ---------- f32 -> bf16 cast ----------
__global__ __launch_bounds__(256) void cast_bf16_kernel(const float* __restrict__ src,
                                                        u16* __restrict__ dst, int n4){
  int i = blockIdx.x*256 + threadIdx.x;
  if (i < n4){
    float4 v = reinterpret_cast<const float4*>(src)[i];
    ushort4 o;
    o.x = f2bf(v.x); o.y = f2bf(v.y); o.z = f2bf(v.z); o.w = f2bf(v.w);
    reinterpret_cast<ushort4*>(dst)[i] = o;
  }
}

// ---------- RoPE (in place, bf16, layout (B, NH, S, D)) ----------
__global__ __launch_bounds__(256) void rope_kernel(u16* __restrict__ X,
                                                   const float* __restrict__ fc,
                                                   const float* __restrict__ fs, int NH){
  int tid = blockIdx.x*256 + threadIdx.x;
  int rr = tid >> 4;                 // row = (b*NH + h)*2048 + s
  int d0 = (tid & 15) * 8;
  int s  = rr & 2047;
  int b  = (rr >> 11) / NH;
  size_t base = (size_t)rr * 256;
  s16x8 x1 = *(const s16x8*)&X[base + d0];
  s16x8 x2 = *(const s16x8*)&X[base + 128 + d0];
  const float* cp = fc + ((size_t)(b*2048 + s))*128 + d0;
  const float* sp = fs + ((size_t)(b*2048 + s))*128 + d0;
  alignas(16) u16 o1[8], o2[8];
  #pragma unroll
  for (int j=0;j<8;j++){
    float c = cp[j], sn = sp[j];
    float a = bf2f((u16)x1[j]);
    float bb = bf2f((u16)x2[j]);
    o1[j] = f2bf(a*c - bb*sn);
    o2[j] = f2bf(a*sn + bb*c);
  }
  *(s16x8*)&X[base + d0]       = *(const s16x8*)o1;
  *(s16x8*)&X[base + 128 + d0] = *(const s16x8*)o2;
}

// ---------- 128x128x32 bf16 GEMM, C = A(M,K) * B(N,K)^T ----------
// MODE 0: epilogue scatters to Q/K/V bf16 layouts (B,H,S,D); MODE 1: plain f32 row-major C.
template<int MODE>
__global__ __launch_bounds__(256,2) void gemm_bt_kernel(
    const u16* __restrict__ A, const u16* __restrict__ Bw,
    int K, int nbn, int Nn,
    float* __restrict__ Cf, u16* __restrict__ Qo, u16* __restrict__ Ko, u16* __restrict__ Vo)
{
  __shared__ u16 As[128*32];
  __shared__ u16 Bs[128*32];
  const int bid = blockIdx.x;
  const int bm = bid / nbn, bn = bid % nbn;
  const int t = threadIdx.x, wvid = t>>6, ln = t&63;
  const int wr = wvid>>1, wc = wvid&1;
  const int frow = ln&15, fk = (ln>>4)*8;

  f32x4 acc[4][4];
  #pragma unroll
  for (int i=0;i<4;i++)
    #pragma unroll
    for (int j=0;j<4;j++) acc[i][j] = f32x4{0.f,0.f,0.f,0.f};

  const int e0 = (wvid*2)*512 + ln*8;
  const int r0 = e0>>5, c0 = e0&31;
  const int e1 = e0 + 512;
  const int r1 = e1>>5, c1 = e1&31;
  const u16* Ap0 = A  + (size_t)(bm*128 + r0)*K + c0;
  const u16* Ap1 = A  + (size_t)(bm*128 + r1)*K + c1;
  const u16* Bp0 = Bw + (size_t)(bn*128 + r0)*K + c0;
  const u16* Bp1 = Bw + (size_t)(bn*128 + r1)*K + c1;
  u16* la0 = &As[(wvid*2+0)*512]; u16* la1 = &As[(wvid*2+1)*512];
  u16* lb0 = &Bs[(wvid*2+0)*512]; u16* lb1 = &Bs[(wvid*2+1)*512];

  for (int k0=0; k0<K; k0+=32){
    gload16(Ap0 + k0, la0);
    gload16(Ap1 + k0, la1);
    gload16(Bp0 + k0, lb0);
    gload16(Bp1 + k0, lb1);
    __syncthreads();
    s16x8 af[4], bfr[4];
    #pragma unroll
    for (int mi=0;mi<4;mi++) af[mi]  = *(const s16x8*)&As[(wr*64+mi*16+frow)*32 + fk];
    #pragma unroll
    for (int ni=0;ni<4;ni++) bfr[ni] = *(const s16x8*)&Bs[(wc*64+ni*16+frow)*32 + fk];
    #pragma unroll
    for (int mi=0;mi<4;mi++)
      #pragma unroll
      for (int ni=0;ni<4;ni++)
        acc[mi][ni] = __builtin_amdgcn_mfma_f32_16x16x32_bf16(af[mi], bfr[ni], acc[mi][ni], 0,0,0);
    __syncthreads();
  }

  const int mbase = bm*128 + wr*64;
  const int nbase = bn*128 + wc*64;
  #pragma unroll
  for (int mi=0;mi<4;mi++){
    #pragma unroll
    for (int ni=0;ni<4;ni++){
      #pragma unroll
      for (int r=0;r<4;r++){
        int m = mbase + mi*16 + (ln>>4)*4 + r;
        int n = nbase + ni*16 + frow;
        if (MODE == 0){
          int b = m >> 11, s = m & 2047;
          u16 v = f2bf(acc[mi][ni][r]);
          if (n < 4096){
            int h = n >> 8, d = n & 255;
            Qo[((((size_t)b*16 + h)*2048 + s) << 8) + d] = v;
          } else if (n < 6144){
            int n2 = n - 4096; int h = n2 >> 8, d = n2 & 255;
            Ko[((((size_t)b*8 + h)*2048 + s) << 8) + d] = v;
          } else {
            int n2 = n - 6144; int h = n2 >> 8, d = n2 & 255;
            Vo[((((size_t)b*8 + h)*2048 + s) << 8) + d] = v;
          }
        } else {
          Cf[(size_t)m*Nn + n] = acc[mi][ni][r];
        }
      }
    }
  }
}

// ---------- causal GQA flash attention ----------
// Q (B,16,S,256) bf16, K/V (B,8,S,256) bf16 -> O (B,S,16,256) bf16
__global__ __launch_bounds__(256,2) void flash_attn_kernel(
    const u16* __restrict__ Qg, const u16* __restrict__ Kg,
    const u16* __restrict__ Vg, u16* __restrict__ Og)
{
  __shared__ u16 Kl[32*264];      // 32 k-rows x 256 (+8 pad)
  __shared__ u16 Vt[256*40];      // V^T: 256 d-rows x 32 k (+8 pad)
  __shared__ u16 Pl[4][16*40];    // per-wave P: 16 q x 32 k (+8 pad)
  const int qb = blockIdx.x, h = blockIdx.y, b = blockIdx.z;
  const int t = threadIdx.x, wvid = t>>6, ln = t&63;
  const int frow = ln&15, g = ln>>4, fk = g*8;
  const u16* Qp = Qg + ((size_t)(b*16 + h) << 19);
  const u16* Kp = Kg + ((size_t)(b*8 + (h>>1)) << 19);
  const u16* Vp = Vg + ((size_t)(b*8 + (h>>1)) << 19);
  const int q0 = qb*64 + wvid*16;

  s16x8 aq[8];
  #pragma unroll
  for (int kk=0;kk<8;kk++)
    aq[kk] = *(const s16x8*)&Qp[(size_t)(q0+frow)*256 + kk*32 + fk];

  f32x4 accO[16];
  #pragma unroll
  for (int i=0;i<16;i++) accO[i] = f32x4{0.f,0.f,0.f,0.f};
  float mrow[4] = {-1e30f,-1e30f,-1e30f,-1e30f};
  float lrow[4] = {0.f,0.f,0.f,0.f};

  const int ntiles = qb*2 + 2;
  for (int kt=0; kt<ntiles; kt++){
    const int kbase = kt*32;
    // stage K: coalesced global reads, padded LDS rows
    #pragma unroll
    for (int i=0;i<4;i++){
      int e = (i*256 + t)*8;
      int r = e >> 8, c = e & 255;
      *(s16x8*)&Kl[r*264 + c] = *(const s16x8*)&Kp[(size_t)(kbase + r)*256 + c];
    }
    // stage V^T: lanes read consecutive d (coalesced), write b128 rows of V^T
    #pragma unroll
    for (int c2=0;c2<4;c2++){
      alignas(16) u16 tmp[8];
      #pragma unroll
      for (int j=0;j<8;j++)
        tmp[j] = Vp[(size_t)(kbase + c2*8 + j)*256 + t];
      *(s16x8*)&Vt[t*40 + c2*8] = *(const s16x8*)tmp;
    }
    __syncthreads();

    if (kbase <= q0 + 15){
      // QK^T: 16x32 scores per wave
      f32x4 sc[2];
      sc[0] = f32x4{0.f,0.f,0.f,0.f};
      sc[1] = f32x4{0.f,0.f,0.f,0.f};
      #pragma unroll
      for (int kb=0;kb<2;kb++)
        #pragma unroll
        for (int kk=0;kk<8;kk++){
          s16x8 bk = *(const s16x8*)&Kl[(kb*16+frow)*264 + kk*32 + fk];
          sc[kb] = __builtin_amdgcn_mfma_f32_16x16x32_bf16(aq[kk], bk, sc[kb], 0,0,0);
        }

      float mx[4], psum[4], scale[4];
      #pragma unroll
      for (int r=0;r<4;r++){
        const int qrow = q0 + g*4 + r;
        float s0 = sc[0][r] * 0.0625f;
        float s1 = sc[1][r] * 0.0625f;
        if (kbase + frow > qrow)      s0 = -1e30f;
        if (kbase + 16 + frow > qrow) s1 = -1e30f;
        sc[0][r] = s0; sc[1][r] = s1;
        mx[r] = fmaxf(s0, s1);
      }
      #pragma unroll
      for (int m=1;m<16;m<<=1)
        #pragma unroll
        for (int r=0;r<4;r++)
          mx[r] = fmaxf(mx[r], __shfl_xor(mx[r], m));
      #pragma unroll
      for (int r=0;r<4;r++){
        float mn = fmaxf(mrow[r], mx[r]);
        scale[r] = __expf(mrow[r] - mn);
        mrow[r] = mn;
        float p0 = __expf(sc[0][r] - mn);
        float p1 = __expf(sc[1][r] - mn);
        Pl[wvid][(g*4+r)*40 + frow]      = f2bf(p0);
        Pl[wvid][(g*4+r)*40 + 16 + frow] = f2bf(p1);
        psum[r] = p0 + p1;
      }
      #pragma unroll
      for (int m=1;m<16;m<<=1)
        #pragma unroll
        for (int r=0;r<4;r++)
          psum[r] += __shfl_xor(psum[r], m);
      #pragma unroll
      for (int r=0;r<4;r++)
        lrow[r] = lrow[r]*scale[r] + psum[r];
      #pragma unroll
      for (int nb=0;nb<16;nb++)
        #pragma unroll
        for (int r=0;r<4;r++)
          accO[nb][r] *= scale[r];

      asm volatile("s_waitcnt lgkmcnt(0)" ::: "memory");
      s16x8 pf = *(const s16x8*)&Pl[wvid][frow*40 + fk];
      #pragma unroll
      for (int nb=0;nb<16;nb++){
        s16x8 vf = *(const s16x8*)&Vt[(nb*16+frow)*40 + fk];
        accO[nb] = __builtin_amdgcn_mfma_f32_16x16x32_bf16(pf, vf, accO[nb], 0,0,0);
      }
    }
    __syncthreads();
  }

  float rl[4];
  #pragma unroll
  for (int r=0;r<4;r++) rl[r] = 1.0f / lrow[r];
  #pragma unroll
  for (int nb=0;nb<16;nb++)
    #pragma unroll
    for (int r=0;r<4;r++){
      int qrow = q0 + g*4 + r;
      Og[(((size_t)(b*2048 + qrow)*16 + h) << 8) + nb*16 + frow] = f2bf(accO[nb][r] * rl[r]);
    }
}

// ---------- launch ----------
extern "C" void kernel_launch(void* const* d_in, const int* in_sizes, int n_in,
                              void* d_out, int out_size, void* d_ws, size_t ws_size,
                              hipStream_t stream) {
  const float* hidden = (const float*)d_in[0];
  const float* fcos   = (const float*)d_in[1];
  const float* fsin   = (const float*)d_in[2];
  // d_in[3] = mask (causal, reimplemented analytically)
  const float* wq = (const float*)d_in[4];
  const float* wk = (const float*)d_in[5];
  const float* wv = (const float*)d_in[6];
  const float* wo = (const float*)d_in[7];
  float* out = (float*)d_out;

  char* ws = (char*)d_ws;
  u16* Xb   = (u16*)(ws);                  // 8192x3072             50331648 B
  u16* Wcat = (u16*)(ws + 50331648);       // 8192x3072 (q|k|v)    50331648 B
  u16* Wob  = (u16*)(ws + 100663296);      // 3072x4096             25165824 B
  u16* Qb   = (u16*)(ws + 125829120);      // (4,16,2048,256)       67108864 B
  u16* Kb   = (u16*)(ws + 192937984);      // (4,8,2048,256)        33554432 B
  u16* Vb   = (u16*)(ws + 226492416);      // (4,8,2048,256)        33554432 B
  u16* AOb  = (u16*)(ws + 260046848);      // (4,2048,16,256)       67108864 B
  // total ws needed: 327155712 B

  // casts
  cast_bf16_kernel<<<24576, 256, 0, stream>>>(hidden, Xb, 6291456);
  cast_bf16_kernel<<<12288, 256, 0, stream>>>(wq, Wcat,              3145728);
  cast_bf16_kernel<<< 6144, 256, 0, stream>>>(wk, Wcat + 12582912,   1572864);
  cast_bf16_kernel<<< 6144, 256, 0, stream>>>(wv, Wcat + 18874368,   1572864);
  cast_bf16_kernel<<<12288, 256, 0, stream>>>(wo, Wob,               3145728);

  // fused QKV projection (M=8192, N=8192, K=3072), scatter epilogue
  gemm_bt_kernel<0><<<64*64, 256, 0, stream>>>(Xb, Wcat, 3072, 64, 8192,
                                               nullptr, Qb, Kb, Vb);

  // RoPE in place on Q and K
  rope_kernel<<<8192, 256, 0, stream>>>(Qb, fcos, fsin, 16);
  rope_kernel<<<4096, 256, 0, stream>>>(Kb, fcos, fsin, 8);

  // causal GQA flash attention
  flash_attn_kernel<<<dim3(32,16,4), 256, 0, stream>>>(Qb, Kb, Vb, AOb);

  // output projection (M=8192, N=3072, K=4096) -> f32
  gemm_bt_kernel<1><<<64*24, 256, 0, stream>>>(AOb, Wob, 4096, 24, 3072,
                                               out, nullptr, nullptr, nullptr);
}